// Round 2
// baseline (441.062 us; speedup 1.0000x reference)
//
#include <hip/hip_runtime.h>

// CRF forward (partition fn), B=512, T=512, L=102 (start=100, stop=101).
// R9 (resubmit; previous bench was an infra failure): software-pipeline
// rotation of R8's linear-domain recurrence.
//   Q_t[j] = E_j(t) * sum_k Mhat[j,k] Q_{t-1}[k] * rcp(R)*2^-8
// The shadow work (DPP wave-sum of q_{t-1}, rcp/log2, exp for E_t, logit
// prefetch) is textually INTERLEAVED with the 13 DOT groups of step t,
// in one barrier-free scheduling region, so its dependency chains hide
// under the 104 dot2 issue stream instead of serializing at the bottom of
// the loop body (in-order issue => the old structure paid the full DPP +
// transcendental chain latency every step).
// Serial path per step: ds_read Q -> 104 dot2 -> 2 mul -> cvt -> ds_write.
// One wave per batch element, zero s_barriers.

typedef _Float16 half2_t __attribute__((ext_vector_type(2)));

#define CRF_L 102
#define CRF_RP 104
#define CRF_START 100
#define CRF_STOP 101
#define NEG_BIG (-1.0e30f)
#define LN2F 0.6931471805599453f

#define REP13(X) X(0) X(1) X(2) X(3) X(4) X(5) X(6) X(7) X(8) X(9) X(10) X(11) X(12)

#define FDOT2(a, b, c) __builtin_amdgcn_fdot2((a), (b), (c), false)

template <int CTRL>
__device__ __forceinline__ float dpp_add_step(float x) {
    int xi = __builtin_bit_cast(int, x);
    int yi = __builtin_amdgcn_update_dpp(0, xi, CTRL, 0xf, 0xf, true);
    return x + __builtin_bit_cast(float, yi);
}
__device__ __forceinline__ float wave_sum64(float v) {
    v = dpp_add_step<0x111>(v);  // row_shr:1
    v = dpp_add_step<0x112>(v);  // row_shr:2
    v = dpp_add_step<0x114>(v);  // row_shr:4
    v = dpp_add_step<0x118>(v);  // row_shr:8
    v = dpp_add_step<0x142>(v);  // row_bcast:15
    v = dpp_add_step<0x143>(v);  // row_bcast:31
    return __builtin_bit_cast(float,
        __builtin_amdgcn_readlane(__builtin_bit_cast(int, v), 63));
}

__device__ __forceinline__ half2_t mk2(const float* rowp, int k, float rmx) {
    float e0 = (k + 0 < CRF_L) ? __expf(rowp[k + 0] - rmx) : 0.f;
    float e1 = (k + 1 < CRF_L) ? __expf(rowp[k + 1] - rmx) : 0.f;
    return (half2_t){(_Float16)e0, (_Float16)e1};
}

__attribute__((amdgpu_waves_per_eu(1, 1)))
__launch_bounds__(64)
__global__ void crf_forward_kernel(const float* __restrict__ logits,
                                   const float* __restrict__ trans,
                                   const int* __restrict__ lens,
                                   float* __restrict__ out,
                                   int B, int T) {
    const int b    = blockIdx.x;
    const int lane = threadIdx.x;          // 0..63
    const int r0   = 2 * lane;
    const int r1   = 2 * lane + 1;
    const bool valid = (lane < 51);        // rows 0..101

    __shared__ __align__(16) float TS[CRF_L * CRF_RP];   // trans, padded rows
    __shared__ __align__(16) _Float16 Q[112];            // 13 float4 read span

    // ---- stage trans into LDS (coalesced, setup-only) ----
    #pragma unroll 4
    for (int r = 0; r < CRF_L; ++r)
        for (int c = lane; c < CRF_L; c += 64)
            TS[CRF_RP * r + c] = trans[CRF_L * r + c];

    // ---- init Q (all 112 slots; Q0 = onehot(START)) ----
    if (lane < 56) {
        int i0 = 2 * lane;
        Q[i0]     = (_Float16)((i0 == CRF_START) ? 1.f : 0.f);
        Q[i0 + 1] = (_Float16)0.f;
    }
    __builtin_amdgcn_wave_barrier();

    // ---- rowmax + pack Mhat into 104 named half2 registers ----
    const float* rowA = &TS[CRF_RP * (valid ? r0 : 0)];
    const float* rowB = &TS[CRF_RP * (valid ? r1 : 0)];
    float rmax0 = NEG_BIG, rmax1 = NEG_BIG;
    #pragma unroll
    for (int k = 0; k < CRF_L; ++k) {
        rmax0 = fmaxf(rmax0, rowA[k]);
        rmax1 = fmaxf(rmax1, rowB[k]);
    }

#define DECLM(j) half2_t ma##j##_0, ma##j##_1, ma##j##_2, ma##j##_3, \
                         mb##j##_0, mb##j##_1, mb##j##_2, mb##j##_3;
    REP13(DECLM)
#undef DECLM
#define PACKJ(j) \
    ma##j##_0 = mk2(rowA, 8*(j)+0, rmax0); ma##j##_1 = mk2(rowA, 8*(j)+2, rmax0); \
    ma##j##_2 = mk2(rowA, 8*(j)+4, rmax0); ma##j##_3 = mk2(rowA, 8*(j)+6, rmax0); \
    mb##j##_0 = mk2(rowB, 8*(j)+0, rmax1); mb##j##_1 = mk2(rowB, 8*(j)+2, rmax1); \
    mb##j##_2 = mk2(rowB, 8*(j)+4, rmax1); mb##j##_3 = mk2(rowB, 8*(j)+6, rmax1);
    REP13(PACKJ)
#undef PACKJ

    // E uses logit + rowmax; invalid rows get -inf so E==0 (kills all selects)
    const float erm0 = (valid)              ? rmax0 : NEG_BIG;  // rows 102/103
    const float erm1 = (valid && r1 < CRF_L) ? rmax1 : NEG_BIG;

    const int len = min(lens[b], T);
    const float* lg = logits + (size_t)b * (size_t)T * (size_t)CRF_L;
    const int loff = valid ? r0 : 0;

    // depth-3 logit prefetch: lgA = logits[t], lgB = [t+1], lgC = [t+2]
    float2 lgA = *reinterpret_cast<const float2*>(lg + loff);
    float2 lgB = *reinterpret_cast<const float2*>(lg + (size_t)min(1, T - 1) * CRF_L + loff);
    float2 lgC = *reinterpret_cast<const float2*>(lg + (size_t)min(2, T - 1) * CRF_L + loff);

    // q registers hold q_{t-1} entering iteration t; start = onehot(START).
    // (normalization of q_{t-1} is computed inside iteration t, interleaved
    //  with the dot phase; for t=0 this reproduces R=1 -> invRs=2^-8, l2R=0)
    float q0 = (r0 == CRF_START) ? 1.f : 0.f;
    float q1 = 0.f;
    float Lacc = 0.f;
    const int sidx = min(r0, 102);   // lanes >=52 alias the zero pad (benign)

    for (int t = 0; t < len; ++t) {
        // ---- dot(Mhat[r,:], Q[:]) both rows: 13 b128 broadcasts, 104 dot2,
        //      with the shadow work for THIS step interleaved (off-path ops
        //      fill the dot2 issue stream's dependency gaps) ----
        const float4* P4 = reinterpret_cast<const float4*>(&Q[0]);
        float c0 = 0.f, c1 = 0.f, c2 = 0.f, c3 = 0.f;
        float d0 = 0.f, d1 = 0.f, d2 = 0.f, d3 = 0.f;
#define DOT(j) { float4 q = P4[j]; \
        half2_t q0h = __builtin_bit_cast(half2_t, q.x); \
        half2_t q1h = __builtin_bit_cast(half2_t, q.y); \
        half2_t q2h = __builtin_bit_cast(half2_t, q.z); \
        half2_t q3h = __builtin_bit_cast(half2_t, q.w); \
        c0 = FDOT2(ma##j##_0, q0h, c0); c1 = FDOT2(ma##j##_1, q1h, c1); \
        c2 = FDOT2(ma##j##_2, q2h, c2); c3 = FDOT2(ma##j##_3, q3h, c3); \
        d0 = FDOT2(mb##j##_0, q0h, d0); d1 = FDOT2(mb##j##_1, q1h, d1); \
        d2 = FDOT2(mb##j##_2, q2h, d2); d3 = FDOT2(mb##j##_3, q3h, d3); }
        DOT(0)
        DOT(1)
        float s = q0 + q1;                 // wave-sum of q_{t-1}
        DOT(2)
        s = dpp_add_step<0x111>(s);
        DOT(3)
        s = dpp_add_step<0x112>(s);
        DOT(4)
        s = dpp_add_step<0x114>(s);
        DOT(5)
        s = dpp_add_step<0x118>(s);
        DOT(6)
        s = dpp_add_step<0x142>(s);
        DOT(7)
        s = dpp_add_step<0x143>(s);
        DOT(8)
        float R = __builtin_bit_cast(float,
            __builtin_amdgcn_readlane(__builtin_bit_cast(int, s), 63));
        DOT(9)
        R = fmaxf(R, 1e-30f);
        float invRs = __builtin_amdgcn_rcpf(R) * 0.00390625f;  // rcp(R)*2^-8
        DOT(10)
        float l2R = __log2f(R);
        DOT(11)
        float ecx = __expf(lgA.x + erm0);  // E for THIS step t
        float ecy = __expf(lgA.y + erm1);
        DOT(12)
#undef DOT
        lgA = lgB; lgB = lgC;              // rotate prefetch pipeline
        lgC = *reinterpret_cast<const float2*>(
            lg + (size_t)min(t + 3, T - 1) * CRF_L + loff);

        float dot0 = (c0 + c1) + (c2 + c3);
        float dot1 = (d0 + d1) + (d2 + d3);

        // ---- linear-domain update (factor R*2^8 logged; +8 folded to end) --
        Lacc += l2R;
        q0 = (dot0 * ecx) * invRs;
        q1 = (dot1 * ecy) * invRs;

        __builtin_amdgcn_wave_barrier();   // keep write below all dot reads
        *reinterpret_cast<half2_t*>(&Q[sidx]) =
            (half2_t){(_Float16)q0, (_Float16)q1};
        __builtin_amdgcn_wave_barrier();
    }

    // ---- epilogue: out = ln2*(Lacc+8*len) + log(sum_j Q_j exp(trans[STOP,j]))
    float ts0 = TS[CRF_RP * CRF_STOP + (valid ? r0 : 0)];
    float ts1 = TS[CRF_RP * CRF_STOP + (valid ? r1 : 0)];
    float e;
    if (len == 0) {
        e = ((r0 == CRF_START) ? __expf(ts0) : 0.f);   // Q0 = onehot(START)
    } else {
        e = q0 * __expf(ts0) + q1 * __expf(ts1);       // invalid lanes: q=0
    }
    float se = wave_sum64(e);

    if (lane == 0)
        out[b] = LN2F * (Lacc + 8.0f * (float)len) + __logf(se);
}

extern "C" void kernel_launch(void* const* d_in, const int* in_sizes, int n_in,
                              void* d_out, int out_size, void* d_ws, size_t ws_size,
                              hipStream_t stream) {
    const float* logits = (const float*)d_in[0];   // [B, T, L] fp32
    const float* trans  = (const float*)d_in[1];   // [L, L] fp32
    const int*   lens   = (const int*)d_in[2];     // [B] int32
    float* out = (float*)d_out;                    // [B] fp32

    const int B = 512;
    const int T = 512;

    crf_forward_kernel<<<dim3(B), dim3(64), 0, stream>>>(
        logits, trans, lens, out, B, T);
}

// Round 3
// 440.825 us; speedup vs baseline: 1.0005x; 1.0005x over previous
//
#include <hip/hip_runtime.h>

// CRF forward (partition fn), B=512, T=512, L=102 (start=100, stop=101).
// R10: 16 accumulator chains (was 8). The 104 fdot2/step previously formed
// 8 dependent chains of depth 13; if fdot2's dependent (f32-accum) latency
// is ~32cy, the dot phase was chain-latency-bound (13x32 = 416cy), not
// issue-bound (208cy). Splitting each row's 4 accumulators into even/odd-j
// pairs gives 16 chains of depth <=7: same-chain re-issue every 32cy, so
// the dot phase is issue-bound again. Only reassociates fp32 adds.
// Linear-domain recurrence (per R8/R9):
//   Q_t[j] = E_j(t) * sum_k Mhat[j,k] Q_{t-1}[k] * rcp(R)*2^-8
// One wave per batch element, zero s_barriers.

typedef _Float16 half2_t __attribute__((ext_vector_type(2)));

#define CRF_L 102
#define CRF_RP 104
#define CRF_START 100
#define CRF_STOP 101
#define NEG_BIG (-1.0e30f)
#define LN2F 0.6931471805599453f

#define REP13(X) X(0) X(1) X(2) X(3) X(4) X(5) X(6) X(7) X(8) X(9) X(10) X(11) X(12)

#define FDOT2(a, b, c) __builtin_amdgcn_fdot2((a), (b), (c), false)

template <int CTRL>
__device__ __forceinline__ float dpp_add_step(float x) {
    int xi = __builtin_bit_cast(int, x);
    int yi = __builtin_amdgcn_update_dpp(0, xi, CTRL, 0xf, 0xf, true);
    return x + __builtin_bit_cast(float, yi);
}
__device__ __forceinline__ float wave_sum64(float v) {
    v = dpp_add_step<0x111>(v);  // row_shr:1
    v = dpp_add_step<0x112>(v);  // row_shr:2
    v = dpp_add_step<0x114>(v);  // row_shr:4
    v = dpp_add_step<0x118>(v);  // row_shr:8
    v = dpp_add_step<0x142>(v);  // row_bcast:15
    v = dpp_add_step<0x143>(v);  // row_bcast:31
    return __builtin_bit_cast(float,
        __builtin_amdgcn_readlane(__builtin_bit_cast(int, v), 63));
}

__device__ __forceinline__ half2_t mk2(const float* rowp, int k, float rmx) {
    float e0 = (k + 0 < CRF_L) ? __expf(rowp[k + 0] - rmx) : 0.f;
    float e1 = (k + 1 < CRF_L) ? __expf(rowp[k + 1] - rmx) : 0.f;
    return (half2_t){(_Float16)e0, (_Float16)e1};
}

__attribute__((amdgpu_waves_per_eu(1, 1)))
__launch_bounds__(64)
__global__ void crf_forward_kernel(const float* __restrict__ logits,
                                   const float* __restrict__ trans,
                                   const int* __restrict__ lens,
                                   float* __restrict__ out,
                                   int B, int T) {
    const int b    = blockIdx.x;
    const int lane = threadIdx.x;          // 0..63
    const int r0   = 2 * lane;
    const int r1   = 2 * lane + 1;
    const bool valid = (lane < 51);        // rows 0..101

    __shared__ __align__(16) float TS[CRF_L * CRF_RP];   // trans, padded rows
    __shared__ __align__(16) _Float16 Q[112];            // 13 float4 read span

    // ---- stage trans into LDS (coalesced, setup-only) ----
    #pragma unroll 4
    for (int r = 0; r < CRF_L; ++r)
        for (int c = lane; c < CRF_L; c += 64)
            TS[CRF_RP * r + c] = trans[CRF_L * r + c];

    // ---- init Q (all 112 slots; Q0 = onehot(START)) ----
    if (lane < 56) {
        int i0 = 2 * lane;
        Q[i0]     = (_Float16)((i0 == CRF_START) ? 1.f : 0.f);
        Q[i0 + 1] = (_Float16)0.f;
    }
    __builtin_amdgcn_wave_barrier();

    // ---- rowmax + pack Mhat into 104 named half2 registers ----
    const float* rowA = &TS[CRF_RP * (valid ? r0 : 0)];
    const float* rowB = &TS[CRF_RP * (valid ? r1 : 0)];
    float rmax0 = NEG_BIG, rmax1 = NEG_BIG;
    #pragma unroll
    for (int k = 0; k < CRF_L; ++k) {
        rmax0 = fmaxf(rmax0, rowA[k]);
        rmax1 = fmaxf(rmax1, rowB[k]);
    }

#define DECLM(j) half2_t ma##j##_0, ma##j##_1, ma##j##_2, ma##j##_3, \
                         mb##j##_0, mb##j##_1, mb##j##_2, mb##j##_3;
    REP13(DECLM)
#undef DECLM
#define PACKJ(j) \
    ma##j##_0 = mk2(rowA, 8*(j)+0, rmax0); ma##j##_1 = mk2(rowA, 8*(j)+2, rmax0); \
    ma##j##_2 = mk2(rowA, 8*(j)+4, rmax0); ma##j##_3 = mk2(rowA, 8*(j)+6, rmax0); \
    mb##j##_0 = mk2(rowB, 8*(j)+0, rmax1); mb##j##_1 = mk2(rowB, 8*(j)+2, rmax1); \
    mb##j##_2 = mk2(rowB, 8*(j)+4, rmax1); mb##j##_3 = mk2(rowB, 8*(j)+6, rmax1);
    REP13(PACKJ)
#undef PACKJ

    // E uses logit + rowmax; invalid rows get -inf so E==0 (kills all selects)
    const float erm0 = (valid)              ? rmax0 : NEG_BIG;  // rows 102/103
    const float erm1 = (valid && r1 < CRF_L) ? rmax1 : NEG_BIG;

    const int len = min(lens[b], T);
    const float* lg = logits + (size_t)b * (size_t)T * (size_t)CRF_L;
    const int loff = valid ? r0 : 0;

    // depth-3 logit prefetch: lgA = logits[t], lgB = [t+1], lgC = [t+2]
    float2 lgA = *reinterpret_cast<const float2*>(lg + loff);
    float2 lgB = *reinterpret_cast<const float2*>(lg + (size_t)min(1, T - 1) * CRF_L + loff);
    float2 lgC = *reinterpret_cast<const float2*>(lg + (size_t)min(2, T - 1) * CRF_L + loff);

    // q registers hold q_{t-1} entering iteration t; start = onehot(START).
    float q0 = (r0 == CRF_START) ? 1.f : 0.f;
    float q1 = 0.f;
    float Lacc = 0.f;
    const int sidx = min(r0, 102);   // lanes >=52 alias the zero pad (benign)

    for (int t = 0; t < len; ++t) {
        // ---- dot(Mhat[r,:], Q[:]): 13 b128 broadcasts, 104 dot2 in
        //      16 accumulator chains (even/odd j), shadow work interleaved ----
        const float4* P4 = reinterpret_cast<const float4*>(&Q[0]);
        float c0 = 0.f, c1 = 0.f, c2 = 0.f, c3 = 0.f;
        float c4 = 0.f, c5 = 0.f, c6 = 0.f, c7 = 0.f;
        float d0 = 0.f, d1 = 0.f, d2 = 0.f, d3 = 0.f;
        float d4 = 0.f, d5 = 0.f, d6 = 0.f, d7 = 0.f;
#define DOTQ(j, CA, CB, CC, CD, DA, DB, DC, DD) { float4 q = P4[j]; \
        half2_t q0h = __builtin_bit_cast(half2_t, q.x); \
        half2_t q1h = __builtin_bit_cast(half2_t, q.y); \
        half2_t q2h = __builtin_bit_cast(half2_t, q.z); \
        half2_t q3h = __builtin_bit_cast(half2_t, q.w); \
        CA = FDOT2(ma##j##_0, q0h, CA); CB = FDOT2(ma##j##_1, q1h, CB); \
        CC = FDOT2(ma##j##_2, q2h, CC); CD = FDOT2(ma##j##_3, q3h, CD); \
        DA = FDOT2(mb##j##_0, q0h, DA); DB = FDOT2(mb##j##_1, q1h, DB); \
        DC = FDOT2(mb##j##_2, q2h, DC); DD = FDOT2(mb##j##_3, q3h, DD); }
#define DOTE(j) DOTQ(j, c0, c1, c2, c3, d0, d1, d2, d3)
#define DOTO(j) DOTQ(j, c4, c5, c6, c7, d4, d5, d6, d7)
        DOTE(0)
        DOTO(1)
        float s = q0 + q1;                 // wave-sum of q_{t-1}
        DOTE(2)
        s = dpp_add_step<0x111>(s);
        DOTO(3)
        s = dpp_add_step<0x112>(s);
        DOTE(4)
        s = dpp_add_step<0x114>(s);
        DOTO(5)
        s = dpp_add_step<0x118>(s);
        DOTE(6)
        s = dpp_add_step<0x142>(s);
        DOTO(7)
        s = dpp_add_step<0x143>(s);
        DOTE(8)
        float R = __builtin_bit_cast(float,
            __builtin_amdgcn_readlane(__builtin_bit_cast(int, s), 63));
        DOTO(9)
        R = fmaxf(R, 1e-30f);
        float invRs = __builtin_amdgcn_rcpf(R) * 0.00390625f;  // rcp(R)*2^-8
        DOTE(10)
        float l2R = __log2f(R);
        DOTO(11)
        float ecx = __expf(lgA.x + erm0);  // E for THIS step t
        float ecy = __expf(lgA.y + erm1);
        DOTE(12)
#undef DOTE
#undef DOTO
#undef DOTQ
        lgA = lgB; lgB = lgC;              // rotate prefetch pipeline
        lgC = *reinterpret_cast<const float2*>(
            lg + (size_t)min(t + 3, T - 1) * CRF_L + loff);

        float dot0 = ((c0 + c4) + (c1 + c5)) + ((c2 + c6) + (c3 + c7));
        float dot1 = ((d0 + d4) + (d1 + d5)) + ((d2 + d6) + (d3 + d7));

        // ---- linear-domain update (factor R*2^8 logged; +8 folded to end) --
        Lacc += l2R;
        q0 = (dot0 * ecx) * invRs;
        q1 = (dot1 * ecy) * invRs;

        __builtin_amdgcn_wave_barrier();   // keep write below all dot reads
        *reinterpret_cast<half2_t*>(&Q[sidx]) =
            (half2_t){(_Float16)q0, (_Float16)q1};
        __builtin_amdgcn_wave_barrier();
    }

    // ---- epilogue: out = ln2*(Lacc+8*len) + log(sum_j Q_j exp(trans[STOP,j]))
    float ts0 = TS[CRF_RP * CRF_STOP + (valid ? r0 : 0)];
    float ts1 = TS[CRF_RP * CRF_STOP + (valid ? r1 : 0)];
    float e;
    if (len == 0) {
        e = ((r0 == CRF_START) ? __expf(ts0) : 0.f);   // Q0 = onehot(START)
    } else {
        e = q0 * __expf(ts0) + q1 * __expf(ts1);       // invalid lanes: q=0
    }
    float se = wave_sum64(e);

    if (lane == 0)
        out[b] = LN2F * (Lacc + 8.0f * (float)len) + __logf(se);
}

extern "C" void kernel_launch(void* const* d_in, const int* in_sizes, int n_in,
                              void* d_out, int out_size, void* d_ws, size_t ws_size,
                              hipStream_t stream) {
    const float* logits = (const float*)d_in[0];   // [B, T, L] fp32
    const float* trans  = (const float*)d_in[1];   // [L, L] fp32
    const int*   lens   = (const int*)d_in[2];     // [B] int32
    float* out = (float*)d_out;                    // [B] fp32

    const int B = 512;
    const int T = 512;

    crf_forward_kernel<<<dim3(B), dim3(64), 0, stream>>>(
        logits, trans, lens, out, B, T);
}